// Round 1
// 1041.502 us; speedup vs baseline: 1.1673x; 1.1673x over previous
//
#include <hip/hip_runtime.h>
#include <cstdint>
#include <cstddef>

#define DI __device__ __forceinline__

typedef unsigned short u16;
typedef u16 u16x8 __attribute__((ext_vector_type(8)));
typedef u16 u16x4 __attribute__((ext_vector_type(4)));
typedef float f32x4 __attribute__((ext_vector_type(4)));
typedef __bf16 bf16x8 __attribute__((ext_vector_type(8)));

constexpr float EPSf  = 1e-5f;
constexpr float SCALE = 1.0f / (5.656854249492381f * 256.0f); // 1/(sqrt(32)*H*W)

DI float bf2f(u16 u) { union { uint32_t i; float f; } v; v.i = ((uint32_t)u) << 16; return v.f; }
DI u16 f2bf(float f) {
    union { float f; uint32_t i; } v; v.f = f;
    uint32_t r = v.i + 0x7fffu + ((v.i >> 16) & 1u);
    return (u16)(r >> 16);
}

DI f32x4 MFMA(bf16x8 a, bf16x8 b, f32x4 c) {
    return __builtin_amdgcn_mfma_f32_16x16x32_bf16(a, b, c, 0, 0, 0);
}

DI int region3(int x) { return x < 12 ? 0 : (x < 14 ? 1 : 2); }

// fast tanh-gelu: 0.5x(1+tanh(s(x+0.044715x^3))) == x*sigmoid(2s(x+...))
DI float gelu_f(float x) {
    float u = 1.5957691216f * x * (1.f + 0.044715f * x * x);
    return x * __builtin_amdgcn_rcpf(1.f + __expf(-u));
}

// ---------------------------------------------------------------------------
// KW: transpose 6 weights [c][d] f32 -> WT [d][c] bf16
// ---------------------------------------------------------------------------
__global__ __launch_bounds__(256) void kw_prep(
        const float* __restrict__ w_q, const float* __restrict__ w_k,
        const float* __restrict__ w_v, const float* __restrict__ w_o,
        const float* __restrict__ w1,  const float* __restrict__ w2,
        u16* __restrict__ wt) {
    __shared__ float lds[128 * 129];
    const float* W;
    switch (blockIdx.x) {
        case 0: W = w_q; break; case 1: W = w_k; break; case 2: W = w_v; break;
        case 3: W = w_o; break; case 4: W = w1;  break; default: W = w2;  break;
    }
    u16* O = wt + blockIdx.x * 16384;
    int tid = threadIdx.x;
    for (int i = 0; i < 16; i++) {
        int flat = i * 1024 + tid * 4;
        float4 vv = *(const float4*)(W + flat);
        int c = flat >> 7, d = flat & 127;
        lds[c * 129 + d + 0] = vv.x; lds[c * 129 + d + 1] = vv.y;
        lds[c * 129 + d + 2] = vv.z; lds[c * 129 + d + 3] = vv.w;
    }
    __syncthreads();
    for (int i = 0; i < 32; i++) {
        int flat2 = i * 512 + tid * 2;
        int d = flat2 >> 7, c = flat2 & 127;
        u16 a = f2bf(lds[c * 129 + d]);
        u16 b = f2bf(lds[(c + 1) * 129 + d]);
        uint32_t pk = (uint32_t)a | ((uint32_t)b << 16);
        *(uint32_t*)(O + flat2) = pk;
    }
}

// ---------------------------------------------------------------------------
// K2: per windowed-token: load+transpose, InstanceNorm, GEMM -> Q,K,V bf16
//     Q/K/V token layout: [xy 256][c 128] bf16
//     After A-frags are in regs, Abuf is reused as:
//       WTs  = Abuf[0 .. 17408)          : staged weight, 128 rows x pitch 136
//       stgw = Abuf[17408 + wave*2176)   : per-wave epilogue tile, 16 x 136
//     Per-wave staging needs NO barriers (LDS is program-ordered in a wave).
// ---------------------------------------------------------------------------
__global__ __launch_bounds__(512) void k2_qkv(
        const float* __restrict__ v, const u16* __restrict__ wt,
        const float* __restrict__ b_q, const float* __restrict__ b_k,
        const float* __restrict__ b_v,
        u16* __restrict__ Qg, u16* __restrict__ Kg, u16* __restrict__ Vg) {
    __shared__ u16 Abuf[256 * 136];
    __shared__ float red[2][4][128];
    __shared__ float stats[2][128];

    int tid = threadIdx.x;
    int wtk = blockIdx.x;                       // windowed token id
    int b = wtk >> 8, n = (wtk >> 4) & 15, t = wtk & 15;
    int wi = n >> 2, wj = n & 3, ti = t >> 2, tj = t & 3;
    int si = (wi * 4 + ti + 2) & 15, sj = (wj * 4 + tj + 2) & 15; // roll -2
    const float* src = v + (size_t)(b * 256 + si * 16 + sj) * 32768;

    // load + transpose to LDS [xy][c], bf16
    int xy = tid & 255, chh = tid >> 8;
    #pragma unroll 4
    for (int g = 0; g < 16; g++) {
        int c0 = chh * 64 + g * 4;
        float x0 = src[(c0 + 0) * 256 + xy];
        float x1 = src[(c0 + 1) * 256 + xy];
        float x2 = src[(c0 + 2) * 256 + xy];
        float x3 = src[(c0 + 3) * 256 + xy];
        u16x4 u; u.x = f2bf(x0); u.y = f2bf(x1); u.z = f2bf(x2); u.w = f2bf(x3);
        *(u16x4*)&Abuf[xy * 136 + c0] = u;
    }
    __syncthreads();
    // stats
    {
        int c = tid & 127, p = tid >> 7;
        float s = 0.f, q = 0.f;
        for (int k = 0; k < 64; k++) {
            float x = bf2f(Abuf[(p * 64 + k) * 136 + c]);
            s += x; q += x * x;
        }
        red[0][p][c] = s; red[1][p][c] = q;
    }
    __syncthreads();
    if (tid < 128) {
        int c = tid;
        float s = red[0][0][c] + red[0][1][c] + red[0][2][c] + red[0][3][c];
        float q = red[1][0][c] + red[1][1][c] + red[1][2][c] + red[1][3][c];
        float mean = s * (1.f / 256.f);
        float var = q * (1.f / 256.f) - mean * mean;
        stats[0][c] = mean; stats[1][c] = rsqrtf(var + EPSf);
    }
    __syncthreads();
    // normalize in place
    for (int g = 0; g < 16; g++) {
        int c0 = chh * 64 + g * 4;
        u16x4 u = *(u16x4*)&Abuf[xy * 136 + c0];
        u.x = f2bf((bf2f(u.x) - stats[0][c0 + 0]) * stats[1][c0 + 0]);
        u.y = f2bf((bf2f(u.y) - stats[0][c0 + 1]) * stats[1][c0 + 1]);
        u.z = f2bf((bf2f(u.z) - stats[0][c0 + 2]) * stats[1][c0 + 2]);
        u.w = f2bf((bf2f(u.w) - stats[0][c0 + 3]) * stats[1][c0 + 3]);
        *(u16x4*)&Abuf[xy * 136 + c0] = u;
    }
    __syncthreads();

    // GEMM: [256 xy x 128 c] x WT -> q,k,v
    int wave = tid >> 6, lane = tid & 63;
    int lrow = lane & 15, quad = lane >> 4;
    bf16x8 afr[2][4];
    for (int mi = 0; mi < 2; mi++) {
        int mt = wave * 2 + mi;
        for (int kt = 0; kt < 4; kt++)
            afr[mi][kt] = *(const bf16x8*)&Abuf[(mt * 16 + lrow) * 136 + kt * 32 + quad * 8];
    }
    __syncthreads();   // all waves have A-frags in regs; Abuf is now staging
    u16* WTs  = Abuf;                          // 128 x pitch-136
    u16* stgw = Abuf + 17408 + wave * 2176;    // per-wave 16 x pitch-136
    for (int w = 0; w < 3; w++) {
        const u16* WTp = wt + w * 16384;
        const float* bias = (w == 0) ? b_q : (w == 1) ? b_k : b_v;
        u16* O = ((w == 0) ? Qg : (w == 1) ? Kg : Vg) + (size_t)wtk * 32768;
        if (w) __syncthreads();                // prior GEMM done reading WTs
        // stage weight into LDS (pitch 136 -> conflict-free B-frag reads)
        for (int i = 0; i < 4; i++) {
            int flat = i * 4096 + tid * 8;
            *(u16x8*)&WTs[(flat >> 7) * 136 + (flat & 127)] =
                *(const u16x8*)&WTp[flat];
        }
        __syncthreads();
        f32x4 acc[2][8];
        for (int mi = 0; mi < 2; mi++)
            for (int nt = 0; nt < 8; nt++) acc[mi][nt] = (f32x4){0.f, 0.f, 0.f, 0.f};
        for (int kt = 0; kt < 4; kt++) {
            for (int nt = 0; nt < 8; nt++) {
                bf16x8 bfr = *(const bf16x8*)&WTs[(nt * 16 + lrow) * 136 + kt * 32 + quad * 8];
                acc[0][nt] = MFMA(afr[0][kt], bfr, acc[0][nt]);
                acc[1][nt] = MFMA(afr[1][kt], bfr, acc[1][nt]);
            }
        }
        for (int mi = 0; mi < 2; mi++) {
            int mt = wave * 2 + mi;
            for (int nt = 0; nt < 8; nt++) {
                int d = nt * 16 + lrow;
                float bv = bias[d];
                for (int r = 0; r < 4; r++)
                    stgw[(quad * 4 + r) * 136 + d] = f2bf(acc[mi][nt][r] + bv);
            }
            // wave-local staging: no barrier needed
            for (int ro = 0; ro < 4; ro++) {
                int flat = ro * 512 + lane * 8;
                *(u16x8*)&O[mt * 2048 + flat] =
                    *(const u16x8*)&stgw[(flat >> 7) * 136 + (flat & 127)];
            }
        }
    }
}

// ---------------------------------------------------------------------------
// K3: partial scores per (b, window, xy-half). Fragments straight from global
//     (each Q/K element is consumed exactly once -> LDS staging was pure
//     overhead at 1 wave/SIMD). 1024 thr = 16 waves = 4 heads x 4 xy-subchunks;
//     cross-wave f32x4 reduce in 12 KB LDS. spart layout unchanged.
// ---------------------------------------------------------------------------
__global__ __launch_bounds__(1024, 4) void k3_scores(
        const u16* __restrict__ Qg, const u16* __restrict__ Kg,
        float* __restrict__ spart) {
    __shared__ f32x4 red3[3][4][64];
    int tid = threadIdx.x;
    int bid = blockIdx.x;                   // 256 = b(8) * n(16) * half(2)
    int b = bid >> 5, n = (bid >> 1) & 15, half = bid & 1;
    int wtb = (b * 16 + n) * 16;
    int lane = tid & 63, wave = tid >> 6;   // 16 waves
    int head = wave & 3, sub = wave >> 2;   // head 0..3, xy-subchunk 0..3
    int lrow = lane & 15, quad = lane >> 4;
    int xyb = half * 128 + sub * 32;
    const u16* Qp = Qg + (size_t)(wtb + lrow) * 32768 + (size_t)xyb * 128 + head * 32 + quad * 8;
    const u16* Kp = Kg + (size_t)(wtb + lrow) * 32768 + (size_t)xyb * 128 + head * 32 + quad * 8;
    f32x4 acc = {0.f, 0.f, 0.f, 0.f};
    #pragma unroll 4
    for (int kt = 0; kt < 32; kt++) {
        bf16x8 aq = *(const bf16x8*)(Qp + kt * 128);
        bf16x8 bk = *(const bf16x8*)(Kp + kt * 128);
        acc = MFMA(aq, bk, acc);
    }
    if (sub) red3[sub - 1][head][lane] = acc;
    __syncthreads();
    if (sub == 0) {
        f32x4 a0 = red3[0][head][lane];
        f32x4 a1 = red3[1][head][lane];
        f32x4 a2 = red3[2][head][lane];
        acc = acc + a0 + a1 + a2;
        float* sp = spart + (size_t)(((half * 8 + b) * 16 + n) * 4 + head) * 256;
        for (int r = 0; r < 4; r++) sp[(quad * 4 + r) * 16 + lrow] = acc[r];
    }
}

// ---------------------------------------------------------------------------
// K4: softmax+mask, o = attn*V, Wo GEMM, + residual v -> v2 bf16 [tok][xy][c]
//     Per-wave epilogue staging: pitch 136, no block barriers.
// ---------------------------------------------------------------------------
__global__ __launch_bounds__(512) void k4_attnout(
        const float* __restrict__ v, const u16* __restrict__ Vg,
        const float* __restrict__ spart, const u16* __restrict__ wt,
        const float* __restrict__ b_o, u16* __restrict__ v2) {
    __shared__ u16 Vc[32768];          // V chunk; [0,17408) reused as staging
    __shared__ u16 Obuf[256 * 136];
    __shared__ float attn[4][16][16];
    int tid = threadIdx.x;
    int bid = blockIdx.x;              // 512
    int b = bid >> 6, n = (bid >> 2) & 15, qtr = bid & 3;
    int wi = n >> 2, wj = n & 3;
    int wtb = (b * 16 + n) * 16;

    if (tid < 64) {
        int h = tid >> 4, t = tid & 15;
        int it = wi * 4 + (t >> 2) , jt = wj * 4 + (t & 3);
        int rt = region3(it) * 3 + region3(jt);
        const float* sp0 = spart + (size_t)(((0 + b) * 16 + n) * 4 + h) * 256 + t * 16;
        const float* sp1 = spart + (size_t)(((8 + b) * 16 + n) * 4 + h) * 256 + t * 16;
        float vals[16]; float mx = -1e30f;
        for (int s = 0; s < 16; s++) {
            int is = wi * 4 + (s >> 2), js = wj * 4 + (s & 3);
            int rs = region3(is) * 3 + region3(js);
            float sc = (sp0[s] + sp1[s]) * SCALE + (rs == rt ? 0.f : -1e9f);
            vals[s] = sc; mx = fmaxf(mx, sc);
        }
        float sum = 0.f;
        for (int s = 0; s < 16; s++) { vals[s] = __expf(vals[s] - mx); sum += vals[s]; }
        float inv = 1.f / sum;
        for (int s = 0; s < 16; s++) attn[h][t][s] = vals[s] * inv;
    }
    __syncthreads();

    int lane = tid & 63, wave = tid >> 6;
    int lrow = lane & 15, quad = lane >> 4;
    const u16* WoT = wt + 3 * 16384;

    for (int sub = 0; sub < 4; sub++) {
        int xyb = qtr * 64 + sub * 16;
        if (sub) __syncthreads();          // prior stgw reads / afr reads done
        for (int it = 0; it < 8; it++) {
            int flat = (it * 512 + tid) * 8;
            int s = flat >> 11, rem = flat & 2047;
            *(u16x8*)&Vc[flat] =
                *(const u16x8*)&Vg[(size_t)(wtb + s) * 32768 + xyb * 128 + rem];
        }
        __syncthreads();
        // o-compute (VALU): o[t][xyl][c] = sum_s attn[h][t][s] * V[s][xyl][c]
        {
            int c = tid & 127, xg = tid >> 7;   // xg 0..3
            int h = c >> 5;
            float vreg[4][16];
            for (int rep = 0; rep < 4; rep++) {
                int xyl = xg * 4 + rep;
                for (int s = 0; s < 16; s++)
                    vreg[rep][s] = bf2f(Vc[s * 2048 + xyl * 128 + c]);
            }
            for (int t = 0; t < 16; t++) {
                float oa0 = 0.f, oa1 = 0.f, oa2 = 0.f, oa3 = 0.f;
                for (int s = 0; s < 16; s++) {
                    float a = attn[h][t][s];
                    oa0 += a * vreg[0][s]; oa1 += a * vreg[1][s];
                    oa2 += a * vreg[2][s]; oa3 += a * vreg[3][s];
                }
                Obuf[(t * 16 + xg * 4 + 0) * 136 + c] = f2bf(oa0);
                Obuf[(t * 16 + xg * 4 + 1) * 136 + c] = f2bf(oa1);
                Obuf[(t * 16 + xg * 4 + 2) * 136 + c] = f2bf(oa2);
                Obuf[(t * 16 + xg * 4 + 3) * 136 + c] = f2bf(oa3);
            }
        }
        __syncthreads();
        // Wo GEMM + residual
        bf16x8 afr[2][4];
        for (int mi = 0; mi < 2; mi++) {
            int mt = wave * 2 + mi;
            for (int kt = 0; kt < 4; kt++)
                afr[mi][kt] = *(const bf16x8*)&Obuf[(mt * 16 + lrow) * 136 + kt * 32 + quad * 8];
        }
        f32x4 acc[2][8];
        for (int mi = 0; mi < 2; mi++)
            for (int nt = 0; nt < 8; nt++) acc[mi][nt] = (f32x4){0.f, 0.f, 0.f, 0.f};
        for (int kt = 0; kt < 4; kt++) {
            for (int nt = 0; nt < 8; nt++) {
                bf16x8 bfr = *(const bf16x8*)&WoT[(nt * 16 + lrow) * 128 + kt * 32 + quad * 8];
                acc[0][nt] = MFMA(afr[0][kt], bfr, acc[0][nt]);
                acc[1][nt] = MFMA(afr[1][kt], bfr, acc[1][nt]);
            }
        }
        u16* stgw = Vc + wave * 2176;      // per-wave 16 x pitch-136
        for (int mi = 0; mi < 2; mi++) {
            int mt = wave * 2 + mi;      // == token t within window
            int sd = (((wi * 4 + (mt >> 2) + 2) & 15) << 4) | ((wj * 4 + (mt & 3) + 2) & 15);
            size_t tokbase = (size_t)(b * 256 + sd) * 32768;
            for (int nt = 0; nt < 8; nt++) {
                int c = nt * 16 + lrow;
                float bv = b_o[c];
                float4 res = *(const float4*)&v[tokbase + (size_t)c * 256 + xyb + quad * 4];
                stgw[(quad * 4 + 0) * 136 + c] = f2bf(acc[mi][nt][0] + bv + res.x);
                stgw[(quad * 4 + 1) * 136 + c] = f2bf(acc[mi][nt][1] + bv + res.y);
                stgw[(quad * 4 + 2) * 136 + c] = f2bf(acc[mi][nt][2] + bv + res.z);
                stgw[(quad * 4 + 3) * 136 + c] = f2bf(acc[mi][nt][3] + bv + res.w);
            }
            // wave-local staging: no barrier needed
            size_t obase = tokbase + (size_t)xyb * 128;
            for (int ro = 0; ro < 4; ro++) {
                int flat = ro * 512 + lane * 8;
                *(u16x8*)&v2[obase + flat] =
                    *(const u16x8*)&stgw[(flat >> 7) * 136 + (flat & 127)];
            }
        }
    }
}

// ---------------------------------------------------------------------------
// K6: per token: norm, W1 GEMM + gelu, W2 GEMM, + residual -> out f32 [c][xy]
//     W1T staged into Hbuf (dead until GEMM1 epilogue); fast gelu.
// ---------------------------------------------------------------------------
__global__ __launch_bounds__(512) void k6_mlp(
        const u16* __restrict__ v2, const u16* __restrict__ wt,
        const float* __restrict__ b1, const float* __restrict__ b2,
        float* __restrict__ out) {
    __shared__ u16 Nbuf[256 * 136];
    __shared__ u16 Hbuf[256 * 136];
    __shared__ float red[2][4][128];
    __shared__ float stats[3][128];
    int tid = threadIdx.x;
    size_t tok = blockIdx.x;
    const u16* src = v2 + tok * 32768;

    for (int it = 0; it < 8; it++) {
        int flat = (it * 512 + tid) * 8;
        int xy = flat >> 7, c = flat & 127;
        *(u16x8*)&Nbuf[xy * 136 + c] = *(const u16x8*)&src[flat];
    }
    __syncthreads();
    {
        int c = tid & 127, p = tid >> 7;
        float s = 0.f, q = 0.f;
        for (int k = 0; k < 64; k++) {
            float x = bf2f(Nbuf[(p * 64 + k) * 136 + c]);
            s += x; q += x * x;
        }
        red[0][p][c] = s; red[1][p][c] = q;
    }
    __syncthreads();
    if (tid < 128) {
        int c = tid;
        float s = red[0][0][c] + red[0][1][c] + red[0][2][c] + red[0][3][c];
        float q = red[1][0][c] + red[1][1][c] + red[1][2][c] + red[1][3][c];
        float mean = s * (1.f / 256.f);
        float var = q * (1.f / 256.f) - mean * mean;
        float rstd = rsqrtf(var + EPSf);
        stats[0][c] = mean; stats[1][c] = rstd; stats[2][c] = (var + EPSf) * rstd; // sd
    }
    __syncthreads();
    {
        int c0 = (tid & 31) * 4, xyB = tid >> 5;
        for (int g = 0; g < 16; g++) {
            int xy = g * 16 + xyB;
            u16x4 u = *(u16x4*)&Nbuf[xy * 136 + c0];
            u.x = f2bf((bf2f(u.x) - stats[0][c0 + 0]) * stats[1][c0 + 0]);
            u.y = f2bf((bf2f(u.y) - stats[0][c0 + 1]) * stats[1][c0 + 1]);
            u.z = f2bf((bf2f(u.z) - stats[0][c0 + 2]) * stats[1][c0 + 2]);
            u.w = f2bf((bf2f(u.w) - stats[0][c0 + 3]) * stats[1][c0 + 3]);
            *(u16x4*)&Nbuf[xy * 136 + c0] = u;
        }
    }
    {   // stage W1T into Hbuf rows 0..127 (pitch 136) — Hbuf dead until GEMM1 epi
        const u16* W1T = wt + 4 * 16384;
        for (int i = 0; i < 4; i++) {
            int flat = i * 4096 + tid * 8;
            *(u16x8*)&Hbuf[(flat >> 7) * 136 + (flat & 127)] = *(const u16x8*)&W1T[flat];
        }
    }
    __syncthreads();

    int wave = tid >> 6, lane = tid & 63;
    int lrow = lane & 15, quad = lane >> 4;
    const u16* W2T = wt + 5 * 16384;

    // GEMM1 (B from staged LDS) + gelu -> Hbuf
    {
        bf16x8 afr[2][4];
        for (int mi = 0; mi < 2; mi++) {
            int mt = wave * 2 + mi;
            for (int kt = 0; kt < 4; kt++)
                afr[mi][kt] = *(const bf16x8*)&Nbuf[(mt * 16 + lrow) * 136 + kt * 32 + quad * 8];
        }
        f32x4 acc[2][8];
        for (int mi = 0; mi < 2; mi++)
            for (int nt = 0; nt < 8; nt++) acc[mi][nt] = (f32x4){0.f, 0.f, 0.f, 0.f};
        for (int kt = 0; kt < 4; kt++) {
            for (int nt = 0; nt < 8; nt++) {
                bf16x8 bfr = *(const bf16x8*)&Hbuf[(nt * 16 + lrow) * 136 + kt * 32 + quad * 8];
                acc[0][nt] = MFMA(afr[0][kt], bfr, acc[0][nt]);
                acc[1][nt] = MFMA(afr[1][kt], bfr, acc[1][nt]);
            }
        }
        __syncthreads();   // all waves done reading W1T before H overwrites it
        for (int mi = 0; mi < 2; mi++) {
            int mt = wave * 2 + mi;
            for (int nt = 0; nt < 8; nt++) {
                int c = nt * 16 + lrow;
                float bv = b1[c];
                for (int r = 0; r < 4; r++) {
                    float x = acc[mi][nt][r] + bv;
                    Hbuf[(mt * 16 + quad * 4 + r) * 136 + c] = f2bf(gelu_f(x));
                }
            }
        }
    }
    // H rows are wave-local (wave w wrote rows w*32..w*32+31, and reads the
    // same rows as GEMM2 A-frags) -> no barrier needed here.
    {
        bf16x8 afr[2][4];
        for (int mi = 0; mi < 2; mi++) {
            int mt = wave * 2 + mi;
            for (int kt = 0; kt < 4; kt++)
                afr[mi][kt] = *(const bf16x8*)&Hbuf[(mt * 16 + lrow) * 136 + kt * 32 + quad * 8];
        }
        f32x4 acc[2][8];
        for (int mi = 0; mi < 2; mi++)
            for (int nt = 0; nt < 8; nt++) acc[mi][nt] = (f32x4){0.f, 0.f, 0.f, 0.f};
        for (int kt = 0; kt < 4; kt++) {
            for (int nt = 0; nt < 8; nt++) {
                bf16x8 bfr = *(const bf16x8*)&W2T[(nt * 16 + lrow) * 128 + kt * 32 + quad * 8];
                acc[0][nt] = MFMA(afr[0][kt], bfr, acc[0][nt]);
                acc[1][nt] = MFMA(afr[1][kt], bfr, acc[1][nt]);
            }
        }
        for (int mi = 0; mi < 2; mi++) {
            int mt = wave * 2 + mi;
            for (int nt = 0; nt < 8; nt++) {
                int c = nt * 16 + lrow;
                float mean = stats[0][c], sd = stats[2][c], bv = b2[c];
                f32x4 o4;
                for (int r = 0; r < 4; r++) {
                    int m = mt * 16 + quad * 4 + r;
                    float n2v = bf2f(Nbuf[m * 136 + c]);
                    o4[r] = acc[mi][nt][r] + bv + n2v * sd + mean;
                }
                *(f32x4*)&out[tok * 32768 + (size_t)c * 256 + mt * 16 + quad * 4] = o4;
            }
        }
    }
}

// ---------------------------------------------------------------------------
extern "C" void kernel_launch(void* const* d_in, const int* in_sizes, int n_in,
                              void* d_out, int out_size, void* d_ws, size_t ws_size,
                              hipStream_t stream) {
    const float* v   = (const float*)d_in[0];
    const float* w_q = (const float*)d_in[1];
    const float* b_q = (const float*)d_in[2];
    const float* w_k = (const float*)d_in[3];
    const float* b_k = (const float*)d_in[4];
    const float* w_v = (const float*)d_in[5];
    const float* b_v = (const float*)d_in[6];
    const float* w_o = (const float*)d_in[7];
    const float* b_o = (const float*)d_in[8];
    const float* w1  = (const float*)d_in[9];
    const float* b1  = (const float*)d_in[10];
    const float* w2  = (const float*)d_in[11];
    const float* b2  = (const float*)d_in[12];

    // workspace layout (~135.5 MB):
    //   wt    : [0, 196608)            6 x 128x128 bf16 transposed weights
    //   spart : [196608, 1245184)      2*8*16*4*256 floats = 1 MB partial scores
    //   Qg/v2 : [1245184, +134217728)  Q (k2->k3), then v2 overlay (k4->k6)
    u16*   wt    = (u16*)d_ws;
    float* spart = (float*)((char*)d_ws + 196608);
    u16*   Qg    = (u16*)((char*)d_ws + 1245184);
    u16*   v2    = Qg;                                     // overlays Q (dead after k3)
    // d_out doubles as scratch for V and K (dead before k6 writes):
    u16*   Vg    = (u16*)d_out;
    u16*   Kg    = (u16*)d_out + 67108864;
    float* out   = (float*)d_out;

    kw_prep  <<<6,    256,  0, stream>>>(w_q, w_k, w_v, w_o, w1, w2, wt);
    k2_qkv   <<<2048, 512,  0, stream>>>(v, wt, b_q, b_k, b_v, Qg, Kg, Vg);
    k3_scores<<<256,  1024, 0, stream>>>(Qg, Kg, spart);
    k4_attnout<<<512, 512,  0, stream>>>(v, Vg, spart, wt, b_o, v2);
    k6_mlp   <<<2048, 512,  0, stream>>>(v2, wt, b1, b2, out);
}